// Round 2
// baseline (47084.430 us; speedup 1.0000x reference)
//
#include <hip/hip_runtime.h>
#include <hip/hip_bf16.h>
#include <math.h>

#define T_STEPS 256
#define B_SZ    256
#define I_SZ    128
#define N_SZ    1024
#define O_SZ    64

#define H_STEP  0.05f
#define OMEGA   6.283185307179586f
#define GAMMA_C 0.1f
#define GR      0.03125f   /* 1/sqrt(1024) */

typedef __attribute__((ext_vector_type(8))) short          short8;
typedef __attribute__((ext_vector_type(4))) short          short4v;
typedef __attribute__((ext_vector_type(4))) unsigned short ushort4v;
typedef __attribute__((ext_vector_type(4))) float          f32x4;

__device__ __forceinline__ float bf2f(unsigned short b) {
    union { unsigned int u; float f; } v; v.u = ((unsigned int)b) << 16; return v.f;
}
__device__ __forceinline__ unsigned short f2bf(float f) {
    union { float f; unsigned int u; } v; v.f = f;
    unsigned int r = v.u + 0x7fffu + ((v.u >> 16) & 1u);
    return (unsigned short)(r >> 16);
}

// ---------------------------------------------------------------------------
// Grid barrier: per-block flag (64B padded), agent-scope atomics.
// Safe: 256 blocks always co-resident (1/CU upper bound by VGPR/LDS).
// ---------------------------------------------------------------------------
__device__ __forceinline__ void grid_barrier(unsigned* flags, unsigned gen,
                                             int tid, int bid)
{
    __syncthreads();                   // block done; stores drained (vmcnt0 @ barrier)
    if (tid == 0) {
        __threadfence();               // release: write back this XCD's L2
        __hip_atomic_store(flags + bid * 16, gen, __ATOMIC_RELAXED,
                           __HIP_MEMORY_SCOPE_AGENT);
    }
    if (tid < 256) {
        while (__hip_atomic_load(flags + tid * 16, __ATOMIC_RELAXED,
                                 __HIP_MEMORY_SCOPE_AGENT) < gen)
            __builtin_amdgcn_s_sleep(1);
    }
    __syncthreads();                   // all 256 flags confirmed
    __threadfence();                   // acquire: invalidate stale L1/L2
}

// ---------------------------------------------------------------------------
// Persistent kernel. 256 blocks x 512 threads (8 waves).
// Block (mt,nt): C-tile [32 rows x 64 cols]. Wave w: k-slice [128w,128w+128),
// W hi/lo fragments register-resident (one-time load). Per substep:
//   A (probe) global->reg, 96 MFMA/wave, LDS k-reduction, fused RK4 epilogue,
//   probe written as bf16 hi/lo (ping-pong), one grid barrier.
// ---------------------------------------------------------------------------
__global__ __launch_bounds__(512, 2) void k_persist(
    const unsigned short* __restrict__ Whg, const unsigned short* __restrict__ Wlg,
    unsigned short* __restrict__ pAh, unsigned short* __restrict__ pAl,
    unsigned short* __restrict__ pBh, unsigned short* __restrict__ pBl,
    const float* __restrict__ bhh, const float* __restrict__ fc0,
    const float* __restrict__ fc1, float* __restrict__ carryg,
    unsigned* __restrict__ flags)
{
    __shared__ float P[8][32][64];   // 64 KB: per-wave C-partials

    const int tid   = threadIdx.x;
    const int bid   = blockIdx.x;
    const int mt    = bid >> 4;            // 16 M-tiles of 32 rows
    const int nt    = bid & 15;            // 16 N-slices of 64 cols
    const int mrow0 = mt * 32;
    const int ncol0 = nt * 64;
    const bool isX  = (mt < 8);

    const int lane  = tid & 63;
    const int w     = tid >> 6;            // wave 0..7
    const int lr    = lane & 15;
    const int kg    = lane >> 4;
    const int kbase = w * 128;             // wave's private k-slice

    // ---- one-time: W fragments into registers (128 VGPR) ----
    short8 wh[4][4], wl[4][4];             // [nf][kf]
    #pragma unroll
    for (int nf = 0; nf < 4; ++nf)
        #pragma unroll
        for (int kf = 0; kf < 4; ++kf) {
            const int off = (ncol0 + nf * 16 + lr) * N_SZ + kbase + kf * 32 + kg * 8;
            wh[nf][kf] = *(const short8*)(Whg + off);
            wl[nf][kf] = *(const short8*)(Wlg + off);
        }

    // ---- epilogue ownership: thread owns 4 contiguous elements ----
    const int er   = tid >> 4;             // local row 0..31
    const int ec   = (tid & 15) * 4;       // local col 0,4,..60
    const int gm   = mrow0 + er;
    const int gn   = ncol0 + ec;
    const int eidx = gm * N_SZ + gn;
    const int pidx = (gm ^ 256) * N_SZ + gn;   // partner half

    float bh4[4], f0r[4], f1r[4];
    #pragma unroll
    for (int j = 0; j < 4; ++j) {
        bh4[j] = bhh[gn + j];
        f0r[j] = isX ? fc0[gm * N_SZ + gn + j] : 0.0f;
        f1r[j] = isX ? fc1[gn + j]             : 0.0f;
    }
    const float sgn = isX ? -OMEGA : OMEGA;

    float cr[4] = {0.f, 0.f, 0.f, 0.f};    // carry (x or y)
    float vv[4] = {0.f, 0.f, 0.f, 0.f};    // current probe value (exact f32)
    float rk[4] = {0.f, 0.f, 0.f, 0.f};    // RK4 accumulator

    unsigned gen = 1;

    for (int t = 0; t < T_STEPS; ++t) {
        #pragma unroll
        for (int sub = 0; sub < 4; ++sub) {
            const unsigned short* inH  = (sub & 1) ? pBh : pAh;
            const unsigned short* inL  = (sub & 1) ? pBl : pAl;
            unsigned short*       outH = (sub & 1) ? pAh : pBh;
            unsigned short*       outL = (sub & 1) ? pAl : pBl;

            // partner probe (8B+8B)
            const ushort4v ohh = *(const ushort4v*)(inH + pidx);
            const ushort4v oll = *(const ushort4v*)(inL + pidx);

            // ---- MFMA: C-partial over wave's k-slice ----
            f32x4 acc[2][4];
            #pragma unroll
            for (int mf = 0; mf < 2; ++mf)
                #pragma unroll
                for (int nf = 0; nf < 4; ++nf)
                    acc[mf][nf] = (f32x4){0.f, 0.f, 0.f, 0.f};

            #pragma unroll
            for (int mf = 0; mf < 2; ++mf) {
                short8 ah[4], al[4];
                #pragma unroll
                for (int kf = 0; kf < 4; ++kf) {
                    const int aoff = (mrow0 + mf * 16 + lr) * N_SZ
                                   + kbase + kf * 32 + kg * 8;
                    ah[kf] = *(const short8*)(inH + aoff);
                    al[kf] = *(const short8*)(inL + aoff);
                }
                #pragma unroll
                for (int kf = 0; kf < 4; ++kf)
                    #pragma unroll
                    for (int nf = 0; nf < 4; ++nf) {
                        acc[mf][nf] = __builtin_amdgcn_mfma_f32_16x16x32_bf16(
                            ah[kf], wh[nf][kf], acc[mf][nf], 0, 0, 0);
                        acc[mf][nf] = __builtin_amdgcn_mfma_f32_16x16x32_bf16(
                            ah[kf], wl[nf][kf], acc[mf][nf], 0, 0, 0);
                        acc[mf][nf] = __builtin_amdgcn_mfma_f32_16x16x32_bf16(
                            al[kf], wh[nf][kf], acc[mf][nf], 0, 0, 0);
                    }
            }

            // ---- cross-wave k-reduction via LDS ----
            #pragma unroll
            for (int mf = 0; mf < 2; ++mf)
                #pragma unroll
                for (int nf = 0; nf < 4; ++nf)
                    #pragma unroll
                    for (int r = 0; r < 4; ++r)
                        P[w][mf * 16 + 4 * kg + r][nf * 16 + lr] = acc[mf][nf][r];
            __syncthreads();

            f32x4 s = {0.f, 0.f, 0.f, 0.f};
            #pragma unroll
            for (int w8 = 0; w8 < 8; ++w8) {
                const f32x4 pv = *(const f32x4*)&P[w8][er][ec];
                s += pv;
            }

            // ---- fused RK4 epilogue (state in registers) ----
            ushort4v hh, ll;
            #pragma unroll
            for (int j = 0; j < 4; ++j) {
                const float own = vv[j];
                const float oth = bf2f(ohh[j]) + bf2f(oll[j]);
                const float rec = GR * (s[j] + bh4[j]);
                const float r2  = own * own + oth * oth;
                float k = (1.0f - r2) * own + sgn * oth + rec - GAMMA_C * own;
                k += (t == 0) ? f0r[j] : f1r[j];     // zero for y-rows

                if (sub == 0)      rk[j] = k;
                else if (sub < 3)  rk[j] += 2.0f * k;

                float vn;
                if (sub < 3) {
                    vn = cr[j] + ((sub == 2) ? H_STEP : 0.5f * H_STEP) * k;
                } else {
                    cr[j] += (H_STEP / 6.0f) * (rk[j] + k);
                    vn = cr[j];
                }
                vv[j] = vn;
                const unsigned short h = f2bf(vn);
                hh[j] = h;
                ll[j] = f2bf(vn - bf2f(h));
            }
            *(ushort4v*)(outH + eidx) = hh;
            *(ushort4v*)(outL + eidx) = ll;

            if (t == T_STEPS - 1 && sub == 3) {
                const f32x4 cv = {cr[0], cr[1], cr[2], cr[3]};
                *(f32x4*)(carryg + eidx) = cv;
            }

            grid_barrier(flags, gen, tid, bid);
            ++gen;
        }
    }
}

// ---------------------------------------------------------------------------
__global__ __launch_bounds__(256) void k_splitW(
    const float* __restrict__ W, unsigned short* __restrict__ Wh,
    unsigned short* __restrict__ Wl)
{
    const int i = (blockIdx.x * 256 + threadIdx.x) * 4;
    const float4 v = *(const float4*)(W + i);
    const float a[4] = {v.x, v.y, v.z, v.w};
    short4v h, l;
    #pragma unroll
    for (int j = 0; j < 4; ++j) {
        const unsigned short hb = f2bf(a[j]);
        h[j] = (short)hb;
        l[j] = (short)f2bf(a[j] - bf2f(hb));
    }
    *(short4v*)(Wh + i) = h;
    *(short4v*)(Wl + i) = l;
}

__global__ __launch_bounds__(256) void k_fc0(
    const float* __restrict__ batch0, const float* __restrict__ Wih,
    const float* __restrict__ bih, float* __restrict__ fc0)
{
    __shared__ float xr[I_SZ];
    const int b = blockIdx.x, tid = threadIdx.x;
    if (tid < I_SZ) xr[tid] = batch0[b * I_SZ + tid];
    __syncthreads();
    #pragma unroll
    for (int j = 0; j < 4; ++j) {
        const int n = tid + 256 * j;
        float s = bih[n];
        const float* wrow = Wih + n * I_SZ;
        for (int k = 0; k < I_SZ; ++k) s += xr[k] * wrow[k];
        fc0[b * N_SZ + n] = tanhf(s);
    }
}

__global__ void k_fc1(const float* __restrict__ bih, float* __restrict__ fc1)
{
    const int i = blockIdx.x * 256 + threadIdx.x;
    if (i < N_SZ) fc1[i] = tanhf(bih[i]);
}

__global__ __launch_bounds__(256) void k_out(
    const float* __restrict__ carry, const float* __restrict__ Who,
    const float* __restrict__ bho, float* __restrict__ out)
{
    __shared__ float xr[N_SZ];
    __shared__ float red[256];
    const int b = blockIdx.x, tid = threadIdx.x;
    #pragma unroll
    for (int j = 0; j < 4; ++j) xr[tid + 256 * j] = carry[b * N_SZ + tid + 256 * j];
    __syncthreads();
    const int o = tid & 63, seg = tid >> 6;
    const float* wrow = Who + o * N_SZ + seg * 256;
    const float* xs = xr + seg * 256;
    float s = 0.f;
    for (int k = 0; k < 256; ++k) s += xs[k] * wrow[k];
    red[tid] = s;
    __syncthreads();
    if (tid < 64)
        out[b * O_SZ + tid] = red[tid] + red[tid + 64] + red[tid + 128]
                            + red[tid + 192] + bho[tid];
}

// ---------------------------------------------------------------------------
extern "C" void kernel_launch(void* const* d_in, const int* in_sizes, int n_in,
                              void* d_out, int out_size, void* d_ws, size_t ws_size,
                              hipStream_t stream)
{
    const float* batch = (const float*)d_in[0];   // (T,B,I)
    const float* Wih   = (const float*)d_in[1];   // (N,I)
    const float* bih   = (const float*)d_in[2];   // (N)
    const float* Whh   = (const float*)d_in[3];   // (N,N)
    const float* bhh   = (const float*)d_in[4];   // (N)
    const float* Who   = (const float*)d_in[5];   // (O,N)
    const float* bho   = (const float*)d_in[6];   // (O)
    float* out = (float*)d_out;

    char* ws = (char*)d_ws;
    const size_t MB1 = 1024 * 1024;
    float*          carry = (float*)(ws + 0 * MB1);            // 2 MB
    unsigned short* pAh   = (unsigned short*)(ws + 2 * MB1);   // 1 MB
    unsigned short* pAl   = (unsigned short*)(ws + 3 * MB1);   // 1 MB
    unsigned short* pBh   = (unsigned short*)(ws + 4 * MB1);   // 1 MB
    unsigned short* pBl   = (unsigned short*)(ws + 5 * MB1);   // 1 MB
    unsigned short* Wh    = (unsigned short*)(ws + 6 * MB1);   // 2 MB
    unsigned short* Wl    = (unsigned short*)(ws + 8 * MB1);   // 2 MB
    float*          fc0   = (float*)(ws + 10 * MB1);           // 1 MB
    float*          fc1   = (float*)(ws + 11 * MB1);           // 4 KB
    unsigned*       flags = (unsigned*)(ws + 11 * MB1 + 65536);// 16 KB

    // zero: initial probe (hi+lo contiguous) and barrier flags
    hipMemsetAsync(pAh,   0, 2 * MB1, stream);
    hipMemsetAsync(flags, 0, 256 * 16 * sizeof(unsigned), stream);

    k_splitW<<<(N_SZ * N_SZ) / (256 * 4), 256, 0, stream>>>(Whh, Wh, Wl);
    k_fc0<<<B_SZ, 256, 0, stream>>>(batch, Wih, bih, fc0);
    k_fc1<<<4, 256, 0, stream>>>(bih, fc1);

    k_persist<<<256, 512, 0, stream>>>(Wh, Wl, pAh, pAl, pBh, pBl,
                                       bhh, fc0, fc1, carry, flags);

    k_out<<<B_SZ, 256, 0, stream>>>(carry, Who, bho, out);
}

// Round 3
// 10605.954 us; speedup vs baseline: 4.4394x; 4.4394x over previous
//
#include <hip/hip_runtime.h>
#include <hip/hip_bf16.h>
#include <math.h>

#define T_STEPS 256
#define B_SZ    256
#define I_SZ    128
#define N_SZ    1024
#define O_SZ    64

#define H_STEP  0.05f
#define OMEGA   6.283185307179586f
#define GAMMA_C 0.1f
#define GR      0.03125f   /* 1/sqrt(1024) */

typedef __attribute__((ext_vector_type(8))) short          short8;
typedef __attribute__((ext_vector_type(4))) short          short4v;
typedef __attribute__((ext_vector_type(4))) unsigned short ushort4v;
typedef __attribute__((ext_vector_type(4))) float          f32x4;
typedef unsigned long long u64;

__device__ __forceinline__ float bf2f(unsigned short b) {
    union { unsigned int u; float f; } v; v.u = ((unsigned int)b) << 16; return v.f;
}
__device__ __forceinline__ unsigned short f2bf(float f) {
    union { float f; unsigned int u; } v; v.f = f;
    unsigned int r = v.u + 0x7fffu + ((v.u >> 16) & 1u);
    return (unsigned short)(r >> 16);
}

// LLC-coherent (agent-scope, relaxed) 8B load/store: sc0+sc1 -> bypass L1/L2,
// served at Infinity Cache. NO cache-invalidating fences anywhere.
__device__ __forceinline__ u64 aload(const void* p) {
    return __hip_atomic_load((const u64*)p, __ATOMIC_RELAXED,
                             __HIP_MEMORY_SCOPE_AGENT);
}
__device__ __forceinline__ void astore(void* p, u64 v) {
    __hip_atomic_store((u64*)p, v, __ATOMIC_RELAXED, __HIP_MEMORY_SCOPE_AGENT);
}
__device__ __forceinline__ short8 aload16(const unsigned short* p) {
    union { u64 u[2]; short8 v; } t;
    t.u[0] = aload(p);
    t.u[1] = aload(p + 4);
    return t.v;
}

// ---------------------------------------------------------------------------
// Persistent kernel. 256 blocks x 512 threads (8 waves), 1 block/CU.
// Block (mt,nt): C-tile [32 rows x 64 cols]; wave w owns k-slice [128w,128w+128)
// with W hi/lo fragments register-resident (loaded once, normal cached loads).
// Probe exchange via LLC-coherent loads/stores. Per substep, per GROUP
// (mt-pair {g,g+8} x 16 nt = 32 blocks): one fetch-add arrival counter +
// one release word (monotonic generations), ~1 us instead of a full-grid
// fence barrier.
// ---------------------------------------------------------------------------
__global__ __launch_bounds__(512, 2) void k_persist(
    const unsigned short* __restrict__ Whg, const unsigned short* __restrict__ Wlg,
    unsigned short* __restrict__ pAh, unsigned short* __restrict__ pAl,
    unsigned short* __restrict__ pBh, unsigned short* __restrict__ pBl,
    const float* __restrict__ bhh, const float* __restrict__ fc0,
    const float* __restrict__ fc1, float* __restrict__ carryg,
    unsigned* __restrict__ sync)
{
    __shared__ float P[8][32][64];   // 64 KB: per-wave C-partials

    const int tid   = threadIdx.x;
    const int bid   = blockIdx.x;
    const int mt    = bid >> 4;            // 16 M-tiles of 32 rows
    const int nt    = bid & 15;            // 16 N-slices of 64 cols
    const int mrow0 = mt * 32;
    const int ncol0 = nt * 64;
    const bool isX  = (mt < 8);
    const int g     = mt & 7;              // sync group (mt-pair)
    unsigned* ctr   = sync + g * 64;       // 256B-strided group lines
    unsigned* rel   = sync + g * 64 + 32;

    const int lane  = tid & 63;
    const int w     = tid >> 6;            // wave 0..7
    const int lr    = lane & 15;
    const int kg    = lane >> 4;
    const int kbase = w * 128;             // wave's private k-slice

    // ---- one-time: W fragments into registers (128 VGPR, cached loads) ----
    short8 wh[4][4], wl[4][4];             // [nf][kf]
    #pragma unroll
    for (int nf = 0; nf < 4; ++nf)
        #pragma unroll
        for (int kf = 0; kf < 4; ++kf) {
            const int off = (ncol0 + nf * 16 + lr) * N_SZ + kbase + kf * 32 + kg * 8;
            wh[nf][kf] = *(const short8*)(Whg + off);
            wl[nf][kf] = *(const short8*)(Wlg + off);
        }

    // ---- epilogue ownership: thread owns 4 contiguous elements ----
    const int er   = tid >> 4;             // local row 0..31
    const int ec   = (tid & 15) * 4;       // local col 0,4,..60
    const int gm   = mrow0 + er;
    const int gn   = ncol0 + ec;
    const int eidx = gm * N_SZ + gn;
    const int pidx = (gm ^ 256) * N_SZ + gn;   // partner half

    float bh4[4], f0r[4], f1r[4];
    #pragma unroll
    for (int j = 0; j < 4; ++j) {
        bh4[j] = bhh[gn + j];
        f0r[j] = isX ? fc0[gm * N_SZ + gn + j] : 0.0f;
        f1r[j] = isX ? fc1[gn + j]             : 0.0f;
    }
    const float sgn = isX ? -OMEGA : OMEGA;

    float cr[4] = {0.f, 0.f, 0.f, 0.f};    // carry (x or y)
    float vv[4] = {0.f, 0.f, 0.f, 0.f};    // current probe value (exact f32)
    float rk[4] = {0.f, 0.f, 0.f, 0.f};    // RK4 accumulator

    unsigned gen = 1;

    for (int t = 0; t < T_STEPS; ++t) {
        #pragma unroll
        for (int sub = 0; sub < 4; ++sub) {
            const unsigned short* inH  = (sub & 1) ? pBh : pAh;
            const unsigned short* inL  = (sub & 1) ? pBl : pAl;
            unsigned short*       outH = (sub & 1) ? pAh : pBh;
            unsigned short*       outL = (sub & 1) ? pAl : pBl;

            // partner probe (LLC-coherent 8B+8B)
            union { u64 u; ushort4v v; } ohh, oll;
            ohh.u = aload(inH + pidx);
            oll.u = aload(inL + pidx);

            // ---- MFMA: C-partial over wave's k-slice ----
            f32x4 acc[2][4];
            #pragma unroll
            for (int mf = 0; mf < 2; ++mf)
                #pragma unroll
                for (int nf = 0; nf < 4; ++nf)
                    acc[mf][nf] = (f32x4){0.f, 0.f, 0.f, 0.f};

            #pragma unroll
            for (int mf = 0; mf < 2; ++mf) {
                short8 ah[4], al[4];
                #pragma unroll
                for (int kf = 0; kf < 4; ++kf) {
                    const int aoff = (mrow0 + mf * 16 + lr) * N_SZ
                                   + kbase + kf * 32 + kg * 8;
                    ah[kf] = aload16(inH + aoff);
                    al[kf] = aload16(inL + aoff);
                }
                #pragma unroll
                for (int kf = 0; kf < 4; ++kf)
                    #pragma unroll
                    for (int nf = 0; nf < 4; ++nf) {
                        acc[mf][nf] = __builtin_amdgcn_mfma_f32_16x16x32_bf16(
                            ah[kf], wh[nf][kf], acc[mf][nf], 0, 0, 0);
                        acc[mf][nf] = __builtin_amdgcn_mfma_f32_16x16x32_bf16(
                            ah[kf], wl[nf][kf], acc[mf][nf], 0, 0, 0);
                        acc[mf][nf] = __builtin_amdgcn_mfma_f32_16x16x32_bf16(
                            al[kf], wh[nf][kf], acc[mf][nf], 0, 0, 0);
                    }
            }

            // ---- cross-wave k-reduction via LDS ----
            #pragma unroll
            for (int mf = 0; mf < 2; ++mf)
                #pragma unroll
                for (int nf = 0; nf < 4; ++nf)
                    #pragma unroll
                    for (int r = 0; r < 4; ++r)
                        P[w][mf * 16 + 4 * kg + r][nf * 16 + lr] = acc[mf][nf][r];
            __syncthreads();

            f32x4 s = {0.f, 0.f, 0.f, 0.f};
            #pragma unroll
            for (int w8 = 0; w8 < 8; ++w8)
                s += *(const f32x4*)&P[w8][er][ec];

            // ---- fused RK4 epilogue (state in registers) ----
            union { u64 u; ushort4v v; } hh, ll;
            #pragma unroll
            for (int j = 0; j < 4; ++j) {
                const float own = vv[j];
                const float oth = bf2f(ohh.v[j]) + bf2f(oll.v[j]);
                const float rec = GR * (s[j] + bh4[j]);
                const float r2  = own * own + oth * oth;
                float k = (1.0f - r2) * own + sgn * oth + rec - GAMMA_C * own;
                k += (t == 0) ? f0r[j] : f1r[j];     // zero for y-rows

                if (sub == 0)      rk[j] = k;
                else if (sub < 3)  rk[j] += 2.0f * k;

                float vn;
                if (sub < 3) {
                    vn = cr[j] + ((sub == 2) ? H_STEP : 0.5f * H_STEP) * k;
                } else {
                    cr[j] += (H_STEP / 6.0f) * (rk[j] + k);
                    vn = cr[j];
                }
                vv[j] = vn;
                const unsigned short h = f2bf(vn);
                hh.v[j] = h;
                ll.v[j] = f2bf(vn - bf2f(h));
            }
            astore(outH + eidx, hh.u);     // LLC-coherent probe publish
            astore(outL + eidx, ll.u);

            if (t == T_STEPS - 1 && sub == 3) {
                const f32x4 cv = {cr[0], cr[1], cr[2], cr[3]};
                *(f32x4*)(carryg + eidx) = cv;
            }

            // ---- group barrier (32 blocks), fence-free ----
            // release: drain own probe stores to LLC, then arrive
            asm volatile("s_waitcnt vmcnt(0)" ::: "memory");
            __syncthreads();               // all waves' stores drained
            if (tid == 0) {
                unsigned old = __hip_atomic_fetch_add(
                    ctr, 1u, __ATOMIC_RELAXED, __HIP_MEMORY_SCOPE_AGENT);
                if (old == gen * 32u - 1u)
                    __hip_atomic_store(rel, gen, __ATOMIC_RELAXED,
                                       __HIP_MEMORY_SCOPE_AGENT);
                while (__hip_atomic_load(rel, __ATOMIC_RELAXED,
                                         __HIP_MEMORY_SCOPE_AGENT) < gen)
                    __builtin_amdgcn_s_sleep(1);
            }
            __syncthreads();
            asm volatile("" ::: "memory"); // no hoisting of next-substep loads
            ++gen;
        }
    }
}

// ---------------------------------------------------------------------------
__global__ __launch_bounds__(256) void k_splitW(
    const float* __restrict__ W, unsigned short* __restrict__ Wh,
    unsigned short* __restrict__ Wl)
{
    const int i = (blockIdx.x * 256 + threadIdx.x) * 4;
    const float4 v = *(const float4*)(W + i);
    const float a[4] = {v.x, v.y, v.z, v.w};
    short4v h, l;
    #pragma unroll
    for (int j = 0; j < 4; ++j) {
        const unsigned short hb = f2bf(a[j]);
        h[j] = (short)hb;
        l[j] = (short)f2bf(a[j] - bf2f(hb));
    }
    *(short4v*)(Wh + i) = h;
    *(short4v*)(Wl + i) = l;
}

__global__ __launch_bounds__(256) void k_fc0(
    const float* __restrict__ batch0, const float* __restrict__ Wih,
    const float* __restrict__ bih, float* __restrict__ fc0)
{
    __shared__ float xr[I_SZ];
    const int b = blockIdx.x, tid = threadIdx.x;
    if (tid < I_SZ) xr[tid] = batch0[b * I_SZ + tid];
    __syncthreads();
    #pragma unroll
    for (int j = 0; j < 4; ++j) {
        const int n = tid + 256 * j;
        float s = bih[n];
        const float* wrow = Wih + n * I_SZ;
        for (int k = 0; k < I_SZ; ++k) s += xr[k] * wrow[k];
        fc0[b * N_SZ + n] = tanhf(s);
    }
}

__global__ void k_fc1(const float* __restrict__ bih, float* __restrict__ fc1)
{
    const int i = blockIdx.x * 256 + threadIdx.x;
    if (i < N_SZ) fc1[i] = tanhf(bih[i]);
}

__global__ __launch_bounds__(256) void k_out(
    const float* __restrict__ carry, const float* __restrict__ Who,
    const float* __restrict__ bho, float* __restrict__ out)
{
    __shared__ float xr[N_SZ];
    __shared__ float red[256];
    const int b = blockIdx.x, tid = threadIdx.x;
    #pragma unroll
    for (int j = 0; j < 4; ++j) xr[tid + 256 * j] = carry[b * N_SZ + tid + 256 * j];
    __syncthreads();
    const int o = tid & 63, seg = tid >> 6;
    const float* wrow = Who + o * N_SZ + seg * 256;
    const float* xs = xr + seg * 256;
    float s = 0.f;
    for (int k = 0; k < 256; ++k) s += xs[k] * wrow[k];
    red[tid] = s;
    __syncthreads();
    if (tid < 64)
        out[b * O_SZ + tid] = red[tid] + red[tid + 64] + red[tid + 128]
                            + red[tid + 192] + bho[tid];
}

// ---------------------------------------------------------------------------
extern "C" void kernel_launch(void* const* d_in, const int* in_sizes, int n_in,
                              void* d_out, int out_size, void* d_ws, size_t ws_size,
                              hipStream_t stream)
{
    const float* batch = (const float*)d_in[0];   // (T,B,I)
    const float* Wih   = (const float*)d_in[1];   // (N,I)
    const float* bih   = (const float*)d_in[2];   // (N)
    const float* Whh   = (const float*)d_in[3];   // (N,N)
    const float* bhh   = (const float*)d_in[4];   // (N)
    const float* Who   = (const float*)d_in[5];   // (O,N)
    const float* bho   = (const float*)d_in[6];   // (O)
    float* out = (float*)d_out;

    char* ws = (char*)d_ws;
    const size_t MB1 = 1024 * 1024;
    float*          carry = (float*)(ws + 0 * MB1);            // 2 MB
    unsigned short* pAh   = (unsigned short*)(ws + 2 * MB1);   // 1 MB
    unsigned short* pAl   = (unsigned short*)(ws + 3 * MB1);   // 1 MB
    unsigned short* pBh   = (unsigned short*)(ws + 4 * MB1);   // 1 MB
    unsigned short* pBl   = (unsigned short*)(ws + 5 * MB1);   // 1 MB
    unsigned short* Wh    = (unsigned short*)(ws + 6 * MB1);   // 2 MB
    unsigned short* Wl    = (unsigned short*)(ws + 8 * MB1);   // 2 MB
    float*          fc0   = (float*)(ws + 10 * MB1);           // 1 MB
    float*          fc1   = (float*)(ws + 11 * MB1);           // 4 KB
    unsigned*       syncb = (unsigned*)(ws + 11 * MB1 + 65536);// 2 KB

    // zero: initial probe (hi+lo contiguous) and sync lines
    hipMemsetAsync(pAh,   0, 2 * MB1, stream);
    hipMemsetAsync(syncb, 0, 8 * 64 * sizeof(unsigned), stream);

    k_splitW<<<(N_SZ * N_SZ) / (256 * 4), 256, 0, stream>>>(Whh, Wh, Wl);
    k_fc0<<<B_SZ, 256, 0, stream>>>(batch, Wih, bih, fc0);
    k_fc1<<<4, 256, 0, stream>>>(bih, fc1);

    k_persist<<<256, 512, 0, stream>>>(Wh, Wl, pAh, pAl, pBh, pBl,
                                       bhh, fc0, fc1, carry, syncb);

    k_out<<<B_SZ, 256, 0, stream>>>(carry, Who, bho, out);
}

// Round 5
// 8121.891 us; speedup vs baseline: 5.7972x; 1.3058x over previous
//
#include <hip/hip_runtime.h>
#include <hip/hip_bf16.h>
#include <math.h>

#define T_STEPS 256
#define B_SZ    256
#define I_SZ    128
#define N_SZ    1024
#define O_SZ    64

#define H_STEP  0.05f
#define OMEGA   6.283185307179586f
#define GAMMA_C 0.1f
#define GR      0.03125f   /* 1/sqrt(1024) */

typedef __attribute__((ext_vector_type(8))) short          short8;
typedef __attribute__((ext_vector_type(4))) short          short4v;
typedef __attribute__((ext_vector_type(4))) unsigned short ushort4v;
typedef __attribute__((ext_vector_type(4))) float          f32x4;
typedef unsigned long long u64;

__device__ __forceinline__ float bf2f(unsigned short b) {
    union { unsigned int u; float f; } v; v.u = ((unsigned int)b) << 16; return v.f;
}
__device__ __forceinline__ unsigned short f2bf(float f) {
    union { float f; unsigned int u; } v; v.f = f;
    unsigned int r = v.u + 0x7fffu + ((v.u >> 16) & 1u);
    return (unsigned short)(r >> 16);
}

// ---------------------------------------------------------------------------
// LLC-coherent 16B loads, batched: 8 loads in flight, one vmcnt(0).
// sc0 sc1 = bypass L1/L2 ownership, served coherently at Infinity Cache
// (same flags the compiler emits for agent-scope atomics; proven rounds 2-3).
// ---------------------------------------------------------------------------
__device__ __forceinline__ void llc_load8(
    const unsigned short* p0, const unsigned short* p1,
    const unsigned short* p2, const unsigned short* p3,
    const unsigned short* p4, const unsigned short* p5,
    const unsigned short* p6, const unsigned short* p7,
    short8* d0, short8* d1, short8* d2, short8* d3,
    short8* d4, short8* d5, short8* d6, short8* d7)
{
    asm volatile(
        "global_load_dwordx4 %0, %8, off sc0 sc1\n\t"
        "global_load_dwordx4 %1, %9, off sc0 sc1\n\t"
        "global_load_dwordx4 %2, %10, off sc0 sc1\n\t"
        "global_load_dwordx4 %3, %11, off sc0 sc1\n\t"
        "global_load_dwordx4 %4, %12, off sc0 sc1\n\t"
        "global_load_dwordx4 %5, %13, off sc0 sc1\n\t"
        "global_load_dwordx4 %6, %14, off sc0 sc1\n\t"
        "global_load_dwordx4 %7, %15, off sc0 sc1\n\t"
        "s_waitcnt vmcnt(0)"
        : "=&v"(*d0), "=&v"(*d1), "=&v"(*d2), "=&v"(*d3),
          "=&v"(*d4), "=&v"(*d5), "=&v"(*d6), "=&v"(*d7)
        : "v"(p0), "v"(p1), "v"(p2), "v"(p3),
          "v"(p4), "v"(p5), "v"(p6), "v"(p7)
        : "memory");
}

// 8x16B + 2x8B (partner probe) in one batch
__device__ __forceinline__ void llc_load8p2(
    const unsigned short* p0, const unsigned short* p1,
    const unsigned short* p2, const unsigned short* p3,
    const unsigned short* p4, const unsigned short* p5,
    const unsigned short* p6, const unsigned short* p7,
    const unsigned short* q0, const unsigned short* q1,
    short8* d0, short8* d1, short8* d2, short8* d3,
    short8* d4, short8* d5, short8* d6, short8* d7,
    u64* e0, u64* e1)
{
    asm volatile(
        "global_load_dwordx4 %0, %10, off sc0 sc1\n\t"
        "global_load_dwordx4 %1, %11, off sc0 sc1\n\t"
        "global_load_dwordx4 %2, %12, off sc0 sc1\n\t"
        "global_load_dwordx4 %3, %13, off sc0 sc1\n\t"
        "global_load_dwordx4 %4, %14, off sc0 sc1\n\t"
        "global_load_dwordx4 %5, %15, off sc0 sc1\n\t"
        "global_load_dwordx4 %6, %16, off sc0 sc1\n\t"
        "global_load_dwordx4 %7, %17, off sc0 sc1\n\t"
        "global_load_dwordx2 %8, %18, off sc0 sc1\n\t"
        "global_load_dwordx2 %9, %19, off sc0 sc1\n\t"
        "s_waitcnt vmcnt(0)"
        : "=&v"(*d0), "=&v"(*d1), "=&v"(*d2), "=&v"(*d3),
          "=&v"(*d4), "=&v"(*d5), "=&v"(*d6), "=&v"(*d7),
          "=&v"(*e0), "=&v"(*e1)
        : "v"(p0), "v"(p1), "v"(p2), "v"(p3),
          "v"(p4), "v"(p5), "v"(p6), "v"(p7),
          "v"(q0), "v"(q1)
        : "memory");
}

__device__ __forceinline__ void llc_store2(unsigned short* a0, u64 v0,
                                           unsigned short* a1, u64 v1)
{
    asm volatile(
        "global_store_dwordx2 %0, %2, off sc0 sc1\n\t"
        "global_store_dwordx2 %1, %3, off sc0 sc1\n\t"
        "s_waitcnt vmcnt(0)"
        :: "v"(a0), "v"(a1), "v"(v0), "v"(v1)
        : "memory");
}

// ---------------------------------------------------------------------------
// Persistent kernel. 256 blocks x 512 threads (8 waves), 1 block/CU.
// bid = nt*16 + mt  (so a sync group {mt,mt^8} x all nt shares bid%8 ->
// one XCD under round-robin dispatch; locality only, not correctness).
// Block (mt,nt): C-tile [32 rows x 64 cols]; wave w owns k-slice
// [128w,128w+128) with W hi/lo fragments register-resident.
// Sync: per-block monotonic flag (64B line). Each block polls only the 17
// flags it depends on (16 same-mt blocks + 1 partner). Reader/writer sets
// are symmetric, so flag>=gen covers RAW and WAR with ping-pong buffers.
// ---------------------------------------------------------------------------
__global__ __launch_bounds__(512, 2) void k_persist(
    const unsigned short* __restrict__ Whg, const unsigned short* __restrict__ Wlg,
    unsigned short* __restrict__ pAh, unsigned short* __restrict__ pAl,
    unsigned short* __restrict__ pBh, unsigned short* __restrict__ pBl,
    const float* __restrict__ bhh, const float* __restrict__ fc0,
    const float* __restrict__ fc1, float* __restrict__ carryg,
    unsigned* __restrict__ flags)
{
    __shared__ float P[8][32][64];   // 64 KB: per-wave C-partials

    const int tid   = threadIdx.x;
    const int bid   = blockIdx.x;
    const int mt    = bid & 15;            // 16 M-tiles of 32 rows
    const int nt    = bid >> 4;            // 16 N-slices of 64 cols
    const int mrow0 = mt * 32;
    const int ncol0 = nt * 64;
    const bool isX  = (mt < 8);

    const int lane  = tid & 63;
    const int w     = tid >> 6;            // wave 0..7
    const int lr    = lane & 15;
    const int kg    = lane >> 4;
    const int kbase = w * 128;             // wave's private k-slice

    // dependency flag pointers (wave 0 polls)
    const unsigned* depf = nullptr;
    if (w == 0) {
        if (lane < 16)       depf = flags + (lane * 16 + mt) * 16;        // (mt, lane)
        else if (lane == 16) depf = flags + (nt * 16 + (mt ^ 8)) * 16;    // partner
    }
    unsigned* myflag = flags + bid * 16;

    // ---- one-time: W fragments into registers (cached loads) ----
    short8 wh[4][4], wl[4][4];             // [nf][kf]
    #pragma unroll
    for (int nf = 0; nf < 4; ++nf)
        #pragma unroll
        for (int kf = 0; kf < 4; ++kf) {
            const int off = (ncol0 + nf * 16 + lr) * N_SZ + kbase + kf * 32 + kg * 8;
            wh[nf][kf] = *(const short8*)(Whg + off);
            wl[nf][kf] = *(const short8*)(Wlg + off);
        }

    // ---- epilogue ownership: thread owns 4 contiguous elements ----
    const int er   = tid >> 4;             // local row 0..31
    const int ec   = (tid & 15) * 4;       // local col 0,4,..60
    const int gm   = mrow0 + er;
    const int gn   = ncol0 + ec;
    const int eidx = gm * N_SZ + gn;
    const int pidx = (gm ^ 256) * N_SZ + gn;   // partner half

    float bh4[4], f0r[4], f1r[4];
    #pragma unroll
    for (int j = 0; j < 4; ++j) {
        bh4[j] = bhh[gn + j];
        f0r[j] = isX ? fc0[gm * N_SZ + gn + j] : 0.0f;
        f1r[j] = isX ? fc1[gn + j]             : 0.0f;
    }
    const float sgn = isX ? -OMEGA : OMEGA;

    float cr[4] = {0.f, 0.f, 0.f, 0.f};    // carry (x or y)
    float vv[4] = {0.f, 0.f, 0.f, 0.f};    // current probe value (exact f32)
    float rk[4] = {0.f, 0.f, 0.f, 0.f};    // RK4 accumulator

    unsigned gen = 1;

    for (int t = 0; t < T_STEPS; ++t) {
        #pragma unroll
        for (int sub = 0; sub < 4; ++sub) {
            const unsigned short* inH  = (sub & 1) ? pBh : pAh;
            const unsigned short* inL  = (sub & 1) ? pBl : pAl;
            unsigned short*       outH = (sub & 1) ? pAh : pBh;
            unsigned short*       outL = (sub & 1) ? pAl : pBl;

            union { u64 u; ushort4v v; } ohh, oll;

            f32x4 acc[2][4];
            #pragma unroll
            for (int mf = 0; mf < 2; ++mf)
                #pragma unroll
                for (int nf = 0; nf < 4; ++nf)
                    acc[mf][nf] = (f32x4){0.f, 0.f, 0.f, 0.f};

            #pragma unroll
            for (int mf = 0; mf < 2; ++mf) {
                short8 ah[4], al[4];
                const unsigned short* ph = inH + (mrow0 + mf * 16 + lr) * N_SZ
                                         + kbase + kg * 8;
                const unsigned short* pl = inL + (mrow0 + mf * 16 + lr) * N_SZ
                                         + kbase + kg * 8;
                if (mf == 0) {
                    llc_load8(ph, ph + 32, ph + 64, ph + 96,
                              pl, pl + 32, pl + 64, pl + 96,
                              &ah[0], &ah[1], &ah[2], &ah[3],
                              &al[0], &al[1], &al[2], &al[3]);
                } else {
                    llc_load8p2(ph, ph + 32, ph + 64, ph + 96,
                                pl, pl + 32, pl + 64, pl + 96,
                                inH + pidx, inL + pidx,
                                &ah[0], &ah[1], &ah[2], &ah[3],
                                &al[0], &al[1], &al[2], &al[3],
                                &ohh.u, &oll.u);
                }
                #pragma unroll
                for (int kf = 0; kf < 4; ++kf)
                    #pragma unroll
                    for (int nf = 0; nf < 4; ++nf) {
                        acc[mf][nf] = __builtin_amdgcn_mfma_f32_16x16x32_bf16(
                            ah[kf], wh[nf][kf], acc[mf][nf], 0, 0, 0);
                        acc[mf][nf] = __builtin_amdgcn_mfma_f32_16x16x32_bf16(
                            ah[kf], wl[nf][kf], acc[mf][nf], 0, 0, 0);
                        acc[mf][nf] = __builtin_amdgcn_mfma_f32_16x16x32_bf16(
                            al[kf], wh[nf][kf], acc[mf][nf], 0, 0, 0);
                    }
            }

            // ---- cross-wave k-reduction via LDS ----
            #pragma unroll
            for (int mf = 0; mf < 2; ++mf)
                #pragma unroll
                for (int nf = 0; nf < 4; ++nf)
                    #pragma unroll
                    for (int r = 0; r < 4; ++r)
                        P[w][mf * 16 + 4 * kg + r][nf * 16 + lr] = acc[mf][nf][r];
            __syncthreads();

            f32x4 s = {0.f, 0.f, 0.f, 0.f};
            #pragma unroll
            for (int w8 = 0; w8 < 8; ++w8)
                s += *(const f32x4*)&P[w8][er][ec];

            // ---- fused RK4 epilogue (state in registers) ----
            union { u64 u; ushort4v v; } hh, ll;
            #pragma unroll
            for (int j = 0; j < 4; ++j) {
                const float own = vv[j];
                const float oth = bf2f(ohh.v[j]) + bf2f(oll.v[j]);
                const float rec = GR * (s[j] + bh4[j]);
                const float r2  = own * own + oth * oth;
                float k = (1.0f - r2) * own + sgn * oth + rec - GAMMA_C * own;
                k += (t == 0) ? f0r[j] : f1r[j];     // zero for y-rows

                if (sub == 0)      rk[j] = k;
                else if (sub < 3)  rk[j] += 2.0f * k;

                float vn;
                if (sub < 3) {
                    vn = cr[j] + ((sub == 2) ? H_STEP : 0.5f * H_STEP) * k;
                } else {
                    cr[j] += (H_STEP / 6.0f) * (rk[j] + k);
                    vn = cr[j];
                }
                vv[j] = vn;
                const unsigned short h = f2bf(vn);
                hh.v[j] = h;
                ll.v[j] = f2bf(vn - bf2f(h));
            }
            llc_store2(outH + eidx, hh.u, outL + eidx, ll.u);  // drained (vmcnt0)

            if (t == T_STEPS - 1 && sub == 3) {
                const f32x4 cv = {cr[0], cr[1], cr[2], cr[3]};
                *(f32x4*)(carryg + eidx) = cv;
            } else {
                // ---- arrival + dependency-set poll ----
                __syncthreads();               // all waves' stores drained
                if (tid == 0)
                    __hip_atomic_store(myflag, gen, __ATOMIC_RELAXED,
                                       __HIP_MEMORY_SCOPE_AGENT);
                if (depf) {
                    while (__hip_atomic_load(depf, __ATOMIC_RELAXED,
                                             __HIP_MEMORY_SCOPE_AGENT) < gen)
                        __builtin_amdgcn_s_sleep(1);
                }
                __syncthreads();               // deps satisfied for all waves
            }
            ++gen;
        }
    }
}

// ---------------------------------------------------------------------------
__global__ __launch_bounds__(256) void k_splitW(
    const float* __restrict__ W, unsigned short* __restrict__ Wh,
    unsigned short* __restrict__ Wl)
{
    const int i = (blockIdx.x * 256 + threadIdx.x) * 4;
    const float4 v = *(const float4*)(W + i);
    const float a[4] = {v.x, v.y, v.z, v.w};
    short4v h, l;
    #pragma unroll
    for (int j = 0; j < 4; ++j) {
        const unsigned short hb = f2bf(a[j]);
        h[j] = (short)hb;
        l[j] = (short)f2bf(a[j] - bf2f(hb));
    }
    *(short4v*)(Wh + i) = h;
    *(short4v*)(Wl + i) = l;
}

__global__ __launch_bounds__(256) void k_fc0(
    const float* __restrict__ batch0, const float* __restrict__ Wih,
    const float* __restrict__ bih, float* __restrict__ fc0)
{
    __shared__ float xr[I_SZ];
    const int b = blockIdx.x, tid = threadIdx.x;
    if (tid < I_SZ) xr[tid] = batch0[b * I_SZ + tid];
    __syncthreads();
    #pragma unroll
    for (int j = 0; j < 4; ++j) {
        const int n = tid + 256 * j;
        float s = bih[n];
        const float* wrow = Wih + n * I_SZ;
        for (int k = 0; k < I_SZ; ++k) s += xr[k] * wrow[k];
        fc0[b * N_SZ + n] = tanhf(s);
    }
}

__global__ void k_fc1(const float* __restrict__ bih, float* __restrict__ fc1)
{
    const int i = blockIdx.x * 256 + threadIdx.x;
    if (i < N_SZ) fc1[i] = tanhf(bih[i]);
}

__global__ __launch_bounds__(256) void k_out(
    const float* __restrict__ carry, const float* __restrict__ Who,
    const float* __restrict__ bho, float* __restrict__ out)
{
    __shared__ float xr[N_SZ];
    __shared__ float red[256];
    const int b = blockIdx.x, tid = threadIdx.x;
    #pragma unroll
    for (int j = 0; j < 4; ++j) xr[tid + 256 * j] = carry[b * N_SZ + tid + 256 * j];
    __syncthreads();
    const int o = tid & 63, seg = tid >> 6;
    const float* wrow = Who + o * N_SZ + seg * 256;
    const float* xs = xr + seg * 256;
    float s = 0.f;
    for (int k = 0; k < 256; ++k) s += xs[k] * wrow[k];
    red[tid] = s;
    __syncthreads();
    if (tid < 64)
        out[b * O_SZ + tid] = red[tid] + red[tid + 64] + red[tid + 128]
                            + red[tid + 192] + bho[tid];
}

// ---------------------------------------------------------------------------
extern "C" void kernel_launch(void* const* d_in, const int* in_sizes, int n_in,
                              void* d_out, int out_size, void* d_ws, size_t ws_size,
                              hipStream_t stream)
{
    const float* batch = (const float*)d_in[0];   // (T,B,I)
    const float* Wih   = (const float*)d_in[1];   // (N,I)
    const float* bih   = (const float*)d_in[2];   // (N)
    const float* Whh   = (const float*)d_in[3];   // (N,N)
    const float* bhh   = (const float*)d_in[4];   // (N)
    const float* Who   = (const float*)d_in[5];   // (O,N)
    const float* bho   = (const float*)d_in[6];   // (O)
    float* out = (float*)d_out;

    char* ws = (char*)d_ws;
    const size_t MB1 = 1024 * 1024;
    float*          carry = (float*)(ws + 0 * MB1);            // 2 MB
    unsigned short* pAh   = (unsigned short*)(ws + 2 * MB1);   // 1 MB
    unsigned short* pAl   = (unsigned short*)(ws + 3 * MB1);   // 1 MB
    unsigned short* pBh   = (unsigned short*)(ws + 4 * MB1);   // 1 MB
    unsigned short* pBl   = (unsigned short*)(ws + 5 * MB1);   // 1 MB
    unsigned short* Wh    = (unsigned short*)(ws + 6 * MB1);   // 2 MB
    unsigned short* Wl    = (unsigned short*)(ws + 8 * MB1);   // 2 MB
    float*          fc0   = (float*)(ws + 10 * MB1);           // 1 MB
    float*          fc1   = (float*)(ws + 11 * MB1);           // 4 KB
    unsigned*       flagb = (unsigned*)(ws + 11 * MB1 + 65536);// 16 KB

    // zero: initial probe (hi+lo contiguous) and flag lines
    hipMemsetAsync(pAh,   0, 2 * MB1, stream);
    hipMemsetAsync(flagb, 0, 256 * 16 * sizeof(unsigned), stream);

    k_splitW<<<(N_SZ * N_SZ) / (256 * 4), 256, 0, stream>>>(Whh, Wh, Wl);
    k_fc0<<<B_SZ, 256, 0, stream>>>(batch, Wih, bih, fc0);
    k_fc1<<<4, 256, 0, stream>>>(bih, fc1);

    k_persist<<<256, 512, 0, stream>>>(Wh, Wl, pAh, pAl, pBh, pBl,
                                       bhh, fc0, fc1, carry, flagb);

    k_out<<<B_SZ, 256, 0, stream>>>(carry, Who, bho, out);
}

// Round 6
// 6634.942 us; speedup vs baseline: 7.0964x; 1.2241x over previous
//
#include <hip/hip_runtime.h>
#include <hip/hip_bf16.h>
#include <math.h>

#define T_STEPS 256
#define B_SZ    256
#define I_SZ    128
#define N_SZ    1024
#define O_SZ    64

#define H_STEP  0.05f
#define OMEGA   6.283185307179586f
#define GAMMA_C 0.1f
#define GR      0.03125f   /* 1/sqrt(1024) */

typedef __attribute__((ext_vector_type(8))) short          short8;
typedef __attribute__((ext_vector_type(4))) short          short4v;
typedef __attribute__((ext_vector_type(4))) unsigned short ushort4v;
typedef __attribute__((ext_vector_type(4))) float          f32x4;
typedef unsigned long long u64;

__device__ __forceinline__ float bf2f(unsigned short b) {
    union { unsigned int u; float f; } v; v.u = ((unsigned int)b) << 16; return v.f;
}
__device__ __forceinline__ unsigned short f2bf(float f) {
    union { float f; unsigned int u; } v; v.f = f;
    unsigned int r = v.u + 0x7fffu + ((v.u >> 16) & 1u);
    return (unsigned short)(r >> 16);
}

__device__ __forceinline__ void llc_store2(unsigned short* a0, u64 v0,
                                           unsigned short* a1, u64 v1)
{
    asm volatile(
        "global_store_dwordx2 %0, %2, off sc0 sc1\n\t"
        "global_store_dwordx2 %1, %3, off sc0 sc1\n\t"
        "s_waitcnt vmcnt(0)"
        :: "v"(a0), "v"(a1), "v"(v0), "v"(v1)
        : "memory");
}

// ---------------------------------------------------------------------------
// Persistent kernel. 256 blocks x 512 threads (8 waves), 1 block/CU.
// bid = nt*16 + mt. Block (mt,nt) owns batch rows [mt*16, mt*16+16) of BOTH
// x (rows mt*16..) and y (rows 256+mt*16..): partner exchange is block-local
// via LDS (double-buffered V). C-tile = 32 rows x 64 cols [nt*64..).
// Wave w owns k-slice [128w,128w+128), W hi/lo fragments register-resident.
// Sync: per-block monotonic flag. Wave w polls only its 2 writers
// (nt' = 2w, 2w+1); union over 8 waves = all 16 deps, joined at the
// P-reduction __syncthreads (covers the WAR check before stores).
// ---------------------------------------------------------------------------
__global__ __launch_bounds__(512, 2) void k_persist(
    const unsigned short* __restrict__ Whg, const unsigned short* __restrict__ Wlg,
    unsigned short* __restrict__ pAh, unsigned short* __restrict__ pAl,
    unsigned short* __restrict__ pBh, unsigned short* __restrict__ pBl,
    const float* __restrict__ bhh, const float* __restrict__ fc0,
    const float* __restrict__ fc1, float* __restrict__ carryg,
    unsigned* __restrict__ flags)
{
    __shared__ float P[8][32][64];   // 64 KB: per-wave C-partials
    __shared__ float V[2][32][64];   // 16 KB: partner probe exchange (dbuf)

    const int tid   = threadIdx.x;
    const int bid   = blockIdx.x;
    const int mt    = bid & 15;            // 16 row-groups (16 x-rows + 16 y-rows)
    const int nt    = bid >> 4;            // 16 N-slices of 64 cols
    const int xrow0 = mt * 16;             // x rows [xrow0, xrow0+16)
    const int yrow0 = 256 + mt * 16;       // y rows
    const int ncol0 = nt * 64;

    const int lane  = tid & 63;
    const int w     = tid >> 6;            // wave 0..7
    const int lr    = lane & 15;
    const int kg    = lane >> 4;
    const int kbase = w * 128;             // wave's private k-slice

    unsigned* myflag = flags + bid * 16;
    const unsigned* depf = (lane < 2)
        ? flags + ((((unsigned)(2 * w + lane)) * 16 + mt) * 16) : nullptr;

    // ---- one-time: W fragments into registers ----
    short8 wh[4][4], wl[4][4];             // [nf][kf]
    #pragma unroll
    for (int nf = 0; nf < 4; ++nf)
        #pragma unroll
        for (int kf = 0; kf < 4; ++kf) {
            const int off = (ncol0 + nf * 16 + lr) * N_SZ + kbase + kf * 32 + kg * 8;
            wh[nf][kf] = *(const short8*)(Whg + off);
            wl[nf][kf] = *(const short8*)(Wlg + off);
        }

    // ---- epilogue ownership: thread owns 4 contiguous elements ----
    const int er   = tid >> 4;             // local row 0..31 (0-15 x, 16-31 y)
    const int ec   = (tid & 15) * 4;       // local col 0,4,..60
    const bool isX = (er < 16);
    const int gm   = isX ? (xrow0 + er) : (yrow0 + (er - 16));
    const int gn   = ncol0 + ec;
    const int eidx = gm * N_SZ + gn;

    float bh4[4], f0r[4], f1r[4];
    #pragma unroll
    for (int j = 0; j < 4; ++j) {
        bh4[j] = bhh[gn + j];
        f0r[j] = isX ? fc0[(xrow0 + er) * N_SZ + gn + j] : 0.0f;
        f1r[j] = isX ? fc1[gn + j]                       : 0.0f;
    }
    const float sgn = isX ? -OMEGA : OMEGA;

    float cr[4] = {0.f, 0.f, 0.f, 0.f};    // carry (x or y)
    float vv[4] = {0.f, 0.f, 0.f, 0.f};    // current probe value (exact f32)
    float rk[4] = {0.f, 0.f, 0.f, 0.f};    // RK4 accumulator

    // init partner-exchange buffers (probe starts at 0)
    *(f32x4*)&V[0][er][ec] = (f32x4){0.f, 0.f, 0.f, 0.f};
    *(f32x4*)&V[1][er][ec] = (f32x4){0.f, 0.f, 0.f, 0.f};
    __syncthreads();

    const int axoff = (xrow0 + lr) * N_SZ + kbase + kg * 8;  // wave A-slice, x rows
    const int ayoff = (yrow0 + lr) * N_SZ + kbase + kg * 8;  // y rows

    unsigned gen = 1;

    for (int t = 0; t < T_STEPS; ++t) {
        #pragma unroll
        for (int sub = 0; sub < 4; ++sub) {
            const unsigned short* inH  = (sub & 1) ? pBh : pAh;
            const unsigned short* inL  = (sub & 1) ? pBl : pAl;
            unsigned short*       outH = (sub & 1) ? pAh : pBh;
            unsigned short*       outL = (sub & 1) ? pAl : pBl;

            // ---- wave-level dependency poll: only this wave's 2 writers ----
            if ((t | sub) != 0) {
                if (lane < 2) {
                    while (__hip_atomic_load(depf, __ATOMIC_RELAXED,
                                             __HIP_MEMORY_SCOPE_AGENT) < gen - 1)
                        __builtin_amdgcn_s_sleep(1);
                }
            }

            // ---- issue all 16 A loads in one batch ----
            short8 axh[4], axl[4], ayh[4], ayl[4];
            {
                const unsigned short* bxh = inH + axoff;
                const unsigned short* bxl = inL + axoff;
                const unsigned short* byh = inH + ayoff;
                const unsigned short* byl = inL + ayoff;
                asm volatile(
                    "global_load_dwordx4 %0, %16, off sc0 sc1\n\t"
                    "global_load_dwordx4 %1, %16, off offset:64 sc0 sc1\n\t"
                    "global_load_dwordx4 %2, %16, off offset:128 sc0 sc1\n\t"
                    "global_load_dwordx4 %3, %16, off offset:192 sc0 sc1\n\t"
                    "global_load_dwordx4 %4, %17, off sc0 sc1\n\t"
                    "global_load_dwordx4 %5, %17, off offset:64 sc0 sc1\n\t"
                    "global_load_dwordx4 %6, %17, off offset:128 sc0 sc1\n\t"
                    "global_load_dwordx4 %7, %17, off offset:192 sc0 sc1\n\t"
                    "global_load_dwordx4 %8, %18, off sc0 sc1\n\t"
                    "global_load_dwordx4 %9, %18, off offset:64 sc0 sc1\n\t"
                    "global_load_dwordx4 %10, %18, off offset:128 sc0 sc1\n\t"
                    "global_load_dwordx4 %11, %18, off offset:192 sc0 sc1\n\t"
                    "global_load_dwordx4 %12, %19, off sc0 sc1\n\t"
                    "global_load_dwordx4 %13, %19, off offset:64 sc0 sc1\n\t"
                    "global_load_dwordx4 %14, %19, off offset:128 sc0 sc1\n\t"
                    "global_load_dwordx4 %15, %19, off offset:192 sc0 sc1"
                    : "=&v"(axh[0]), "=&v"(axh[1]), "=&v"(axh[2]), "=&v"(axh[3]),
                      "=&v"(axl[0]), "=&v"(axl[1]), "=&v"(axl[2]), "=&v"(axl[3]),
                      "=&v"(ayh[0]), "=&v"(ayh[1]), "=&v"(ayh[2]), "=&v"(ayh[3]),
                      "=&v"(ayl[0]), "=&v"(ayl[1]), "=&v"(ayl[2]), "=&v"(ayl[3])
                    : "v"(bxh), "v"(bxl), "v"(byh), "v"(byl)
                    : "memory");
            }

            f32x4 acc[2][4];
            #pragma unroll
            for (int mf = 0; mf < 2; ++mf)
                #pragma unroll
                for (int nf = 0; nf < 4; ++nf)
                    acc[mf][nf] = (f32x4){0.f, 0.f, 0.f, 0.f};

            // ---- x-half MFMAs after first 8 loads land ----
            asm volatile("s_waitcnt vmcnt(8)" ::: "memory");
            __builtin_amdgcn_sched_barrier(0);
            #pragma unroll
            for (int kf = 0; kf < 4; ++kf)
                #pragma unroll
                for (int nf = 0; nf < 4; ++nf) {
                    acc[0][nf] = __builtin_amdgcn_mfma_f32_16x16x32_bf16(
                        axh[kf], wh[nf][kf], acc[0][nf], 0, 0, 0);
                    acc[0][nf] = __builtin_amdgcn_mfma_f32_16x16x32_bf16(
                        axh[kf], wl[nf][kf], acc[0][nf], 0, 0, 0);
                    acc[0][nf] = __builtin_amdgcn_mfma_f32_16x16x32_bf16(
                        axl[kf], wh[nf][kf], acc[0][nf], 0, 0, 0);
                }

            // ---- y-half MFMAs after remaining loads land ----
            asm volatile("s_waitcnt vmcnt(0)" ::: "memory");
            __builtin_amdgcn_sched_barrier(0);
            #pragma unroll
            for (int kf = 0; kf < 4; ++kf)
                #pragma unroll
                for (int nf = 0; nf < 4; ++nf) {
                    acc[1][nf] = __builtin_amdgcn_mfma_f32_16x16x32_bf16(
                        ayh[kf], wh[nf][kf], acc[1][nf], 0, 0, 0);
                    acc[1][nf] = __builtin_amdgcn_mfma_f32_16x16x32_bf16(
                        ayh[kf], wl[nf][kf], acc[1][nf], 0, 0, 0);
                    acc[1][nf] = __builtin_amdgcn_mfma_f32_16x16x32_bf16(
                        ayl[kf], wh[nf][kf], acc[1][nf], 0, 0, 0);
                }

            // ---- cross-wave k-reduction via LDS ----
            #pragma unroll
            for (int mf = 0; mf < 2; ++mf)
                #pragma unroll
                for (int nf = 0; nf < 4; ++nf)
                    #pragma unroll
                    for (int r = 0; r < 4; ++r)
                        P[w][mf * 16 + 4 * kg + r][nf * 16 + lr] = acc[mf][nf][r];
            __syncthreads();   // also: all 16 dep-flags confirmed collectively

            f32x4 s = {0.f, 0.f, 0.f, 0.f};
            #pragma unroll
            for (int w8 = 0; w8 < 8; ++w8)
                s += *(const f32x4*)&P[w8][er][ec];

            // partner probe from LDS (exact f32, written last substep)
            const f32x4 ovv = *(const f32x4*)&V[gen & 1][er ^ 16][ec];

            // ---- fused RK4 epilogue (state in registers) ----
            union { u64 u; ushort4v v; } hh, ll;
            f32x4 nv;
            #pragma unroll
            for (int j = 0; j < 4; ++j) {
                const float own = vv[j];
                const float oth = ovv[j];
                const float rec = GR * (s[j] + bh4[j]);
                const float r2  = own * own + oth * oth;
                float k = (1.0f - r2) * own + sgn * oth + rec - GAMMA_C * own;
                k += (t == 0) ? f0r[j] : f1r[j];     // zero for y-rows

                if (sub == 0)      rk[j] = k;
                else if (sub < 3)  rk[j] += 2.0f * k;

                float vn;
                if (sub < 3) {
                    vn = cr[j] + ((sub == 2) ? H_STEP : 0.5f * H_STEP) * k;
                } else {
                    cr[j] += (H_STEP / 6.0f) * (rk[j] + k);
                    vn = cr[j];
                }
                vv[j] = vn;
                nv[j] = vn;
                const unsigned short h = f2bf(vn);
                hh.v[j] = h;
                ll.v[j] = f2bf(vn - bf2f(h));
            }
            *(f32x4*)&V[(gen + 1) & 1][er][ec] = nv;   // publish partner (local)

            if (t == T_STEPS - 1 && sub == 3) {
                const f32x4 cv = {cr[0], cr[1], cr[2], cr[3]};
                *(f32x4*)(carryg + eidx) = cv;
            } else {
                llc_store2(outH + eidx, hh.u, outL + eidx, ll.u);  // drained
                __syncthreads();               // all waves' stores + V writes done
                if (tid == 0)
                    __hip_atomic_store(myflag, gen, __ATOMIC_RELAXED,
                                       __HIP_MEMORY_SCOPE_AGENT);
            }
            ++gen;
        }
    }
}

// ---------------------------------------------------------------------------
__global__ __launch_bounds__(256) void k_splitW(
    const float* __restrict__ W, unsigned short* __restrict__ Wh,
    unsigned short* __restrict__ Wl)
{
    const int i = (blockIdx.x * 256 + threadIdx.x) * 4;
    const float4 v = *(const float4*)(W + i);
    const float a[4] = {v.x, v.y, v.z, v.w};
    short4v h, l;
    #pragma unroll
    for (int j = 0; j < 4; ++j) {
        const unsigned short hb = f2bf(a[j]);
        h[j] = (short)hb;
        l[j] = (short)f2bf(a[j] - bf2f(hb));
    }
    *(short4v*)(Wh + i) = h;
    *(short4v*)(Wl + i) = l;
}

__global__ __launch_bounds__(256) void k_fc0(
    const float* __restrict__ batch0, const float* __restrict__ Wih,
    const float* __restrict__ bih, float* __restrict__ fc0)
{
    __shared__ float xr[I_SZ];
    const int b = blockIdx.x, tid = threadIdx.x;
    if (tid < I_SZ) xr[tid] = batch0[b * I_SZ + tid];
    __syncthreads();
    #pragma unroll
    for (int j = 0; j < 4; ++j) {
        const int n = tid + 256 * j;
        float s = bih[n];
        const float* wrow = Wih + n * I_SZ;
        for (int k = 0; k < I_SZ; ++k) s += xr[k] * wrow[k];
        fc0[b * N_SZ + n] = tanhf(s);
    }
}

__global__ void k_fc1(const float* __restrict__ bih, float* __restrict__ fc1)
{
    const int i = blockIdx.x * 256 + threadIdx.x;
    if (i < N_SZ) fc1[i] = tanhf(bih[i]);
}

__global__ __launch_bounds__(256) void k_out(
    const float* __restrict__ carry, const float* __restrict__ Who,
    const float* __restrict__ bho, float* __restrict__ out)
{
    __shared__ float xr[N_SZ];
    __shared__ float red[256];
    const int b = blockIdx.x, tid = threadIdx.x;
    #pragma unroll
    for (int j = 0; j < 4; ++j) xr[tid + 256 * j] = carry[b * N_SZ + tid + 256 * j];
    __syncthreads();
    const int o = tid & 63, seg = tid >> 6;
    const float* wrow = Who + o * N_SZ + seg * 256;
    const float* xs = xr + seg * 256;
    float s = 0.f;
    for (int k = 0; k < 256; ++k) s += xs[k] * wrow[k];
    red[tid] = s;
    __syncthreads();
    if (tid < 64)
        out[b * O_SZ + tid] = red[tid] + red[tid + 64] + red[tid + 128]
                            + red[tid + 192] + bho[tid];
}

// ---------------------------------------------------------------------------
extern "C" void kernel_launch(void* const* d_in, const int* in_sizes, int n_in,
                              void* d_out, int out_size, void* d_ws, size_t ws_size,
                              hipStream_t stream)
{
    const float* batch = (const float*)d_in[0];   // (T,B,I)
    const float* Wih   = (const float*)d_in[1];   // (N,I)
    const float* bih   = (const float*)d_in[2];   // (N)
    const float* Whh   = (const float*)d_in[3];   // (N,N)
    const float* bhh   = (const float*)d_in[4];   // (N)
    const float* Who   = (const float*)d_in[5];   // (O,N)
    const float* bho   = (const float*)d_in[6];   // (O)
    float* out = (float*)d_out;

    char* ws = (char*)d_ws;
    const size_t MB1 = 1024 * 1024;
    float*          carry = (float*)(ws + 0 * MB1);            // 2 MB
    unsigned short* pAh   = (unsigned short*)(ws + 2 * MB1);   // 1 MB
    unsigned short* pAl   = (unsigned short*)(ws + 3 * MB1);   // 1 MB
    unsigned short* pBh   = (unsigned short*)(ws + 4 * MB1);   // 1 MB
    unsigned short* pBl   = (unsigned short*)(ws + 5 * MB1);   // 1 MB
    unsigned short* Wh    = (unsigned short*)(ws + 6 * MB1);   // 2 MB
    unsigned short* Wl    = (unsigned short*)(ws + 8 * MB1);   // 2 MB
    float*          fc0   = (float*)(ws + 10 * MB1);           // 1 MB
    float*          fc1   = (float*)(ws + 11 * MB1);           // 4 KB
    unsigned*       flagb = (unsigned*)(ws + 11 * MB1 + 65536);// 16 KB

    // zero: initial probe (hi+lo contiguous) and flag lines
    hipMemsetAsync(pAh,   0, 2 * MB1, stream);
    hipMemsetAsync(flagb, 0, 256 * 16 * sizeof(unsigned), stream);

    k_splitW<<<(N_SZ * N_SZ) / (256 * 4), 256, 0, stream>>>(Whh, Wh, Wl);
    k_fc0<<<B_SZ, 256, 0, stream>>>(batch, Wih, bih, fc0);
    k_fc1<<<4, 256, 0, stream>>>(bih, fc1);

    k_persist<<<256, 512, 0, stream>>>(Wh, Wl, pAh, pAl, pBh, pBl,
                                       bhh, fc0, fc1, carry, flagb);

    k_out<<<B_SZ, 256, 0, stream>>>(carry, Who, bho, out);
}